// Round 1
// baseline (617.604 us; speedup 1.0000x reference)
//
#include <hip/hip_runtime.h>
#include <stdint.h>

#define QN    300
#define WN    10
#define CD    640
#define IJ    196
#define MROWS 1960          // WN*IJ
#define BM    128
#define BN    224           // 196 padded to 14*16
#define BK    32
#define KITERS (CD/BK)      // 20
#define THREADS 512
#define LPAD  40            // LDS row stride in bf16 elems (80B: 2-way max on frag reads)

typedef __attribute__((ext_vector_type(8))) short bf16x8;
typedef __attribute__((ext_vector_type(4))) float f32x4;

__device__ __forceinline__ unsigned short f2bf(float f) {
    uint32_t u = __float_as_uint(f);
    u += 0x7FFFu + ((u >> 16) & 1u);   // RNE
    return (unsigned short)(u >> 16);
}

__global__ __launch_bounds__(THREADS, 4)
void sim_kernel(const float* __restrict__ proto,
                const float* __restrict__ query,
                float* __restrict__ out)
{
    __shared__ unsigned short As[BM][LPAD];
    __shared__ unsigned short Bs[BN][LPAD];
    __shared__ float redA[4][BM];
    __shared__ float redB[2][BN];
    __shared__ float rpS[BM];
    __shared__ float rqS[BN];

    const int tid = threadIdx.x;
    const int m0  = blockIdx.x * BM;
    const int q   = blockIdx.y;

    // ---- A staging map: thread owns column mA, k-chunk krA*8..+7
    const int mA  = tid & (BM - 1);
    const int krA = tid >> 7;                 // 0..3
    const int wiA = m0 + mA;
    const bool va = (wiA < MROWS);
    const int wA  = va ? (wiA / IJ) : 0;
    const int iA  = va ? (wiA - wA * IJ) : 0;
    const float* pA = proto + wA * (CD * IJ) + iA;   // + c*IJ per k

    // ---- B staging map: threads 0..447, column jB, k-chunk krB*16..+15
    const bool tb  = (tid < 448);
    const int jB   = tb ? (tid % BN) : 0;
    const int krB  = tb ? (tid / BN) : 0;     // 0..1
    const bool vb  = tb && (jB < IJ);
    const float* qB = query + q * (CD * IJ) + jB;

    float ssA = 0.f, ssB = 0.f;

    // ---- wave/frag decomposition: wave grid 4(M) x 2(N); wave tile 32x112
    const int wv   = tid >> 6;
    const int lane = tid & 63;
    const int wm0  = (wv >> 1) * 32;
    const int wn0  = (wv & 1) * 112;
    const int fr   = lane & 15;   // A-row / B-col / D-col
    const int fq   = lane >> 4;   // k-chunk select / D row-quad

    f32x4 acc[2][7];
    #pragma unroll
    for (int a = 0; a < 2; a++)
        #pragma unroll
        for (int b = 0; b < 7; b++)
            acc[a][b] = (f32x4){0.f, 0.f, 0.f, 0.f};

    for (int it = 0; it < KITERS; ++it) {
        const int c0 = it * BK;

        // ---- stage A (all 512 threads: 8 fp32 -> bf16x8 -> one b128 write)
        {
            float v[8];
            #pragma unroll
            for (int e = 0; e < 8; e++) {
                int c = c0 + krA * 8 + e;
                v[e] = va ? pA[c * IJ] : 0.f;
            }
            #pragma unroll
            for (int e = 0; e < 8; e++) ssA += v[e] * v[e];
            union { unsigned short s[8]; uint4 u; } pk;
            #pragma unroll
            for (int e = 0; e < 8; e++) pk.s[e] = f2bf(v[e]);
            *(uint4*)&As[mA][krA * 8] = pk.u;
        }
        // ---- stage B (threads 0..447: 16 fp32 in two halves)
        if (tb) {
            #pragma unroll
            for (int h = 0; h < 2; ++h) {
                float v[8];
                #pragma unroll
                for (int e = 0; e < 8; e++) {
                    int c = c0 + krB * 16 + h * 8 + e;
                    v[e] = vb ? qB[c * IJ] : 0.f;
                }
                #pragma unroll
                for (int e = 0; e < 8; e++) ssB += v[e] * v[e];
                union { unsigned short s[8]; uint4 u; } pk;
                #pragma unroll
                for (int e = 0; e < 8; e++) pk.s[e] = f2bf(v[e]);
                *(uint4*)&Bs[jB][krB * 16 + h * 8] = pk.u;
            }
        }
        __syncthreads();

        // ---- MFMA: 2x7 16x16 tiles per wave, full BK=32 per instruction
        bf16x8 af[2], bfv[7];
        #pragma unroll
        for (int tm = 0; tm < 2; tm++)
            af[tm] = *(const bf16x8*)&As[wm0 + tm * 16 + fr][fq * 8];
        #pragma unroll
        for (int tn = 0; tn < 7; tn++)
            bfv[tn] = *(const bf16x8*)&Bs[wn0 + tn * 16 + fr][fq * 8];
        #pragma unroll
        for (int tm = 0; tm < 2; tm++)
            #pragma unroll
            for (int tn = 0; tn < 7; tn++)
                acc[tm][tn] = __builtin_amdgcn_mfma_f32_16x16x32_bf16(
                    af[tm], bfv[tn], acc[tm][tn], 0, 0, 0);
        __syncthreads();
    }

    // ---- norms (sumsq accumulated from ORIGINAL fp32 values during staging)
    redA[krA][mA] = ssA;
    if (tb) redB[krB][jB] = ssB;
    __syncthreads();
    if (tid < BM) {
        rpS[tid] = sqrtf(redA[0][tid] + redA[1][tid] + redA[2][tid] + redA[3][tid]);
    } else if (tid >= 256 && tid < 256 + BN) {
        int j = tid - 256;
        rqS[j] = sqrtf(redB[0][j] + redB[1][j]);
    }
    __syncthreads();

    // ---- epilogue: sim = dot / max(rp*rq, eps); masked exact coverage
    #pragma unroll
    for (int tm = 0; tm < 2; tm++) {
        #pragma unroll
        for (int tn = 0; tn < 7; tn++) {
            #pragma unroll
            for (int r = 0; r < 4; r++) {
                int rl = wm0 + tm * 16 + fq * 4 + r;   // local row (wi)
                int cl = wn0 + tn * 16 + fr;           // local col (j)
                int wi = m0 + rl;
                if (wi < MROWS && cl < IJ) {
                    float denom = fmaxf(rpS[rl] * rqS[cl], 1e-8f);
                    out[(size_t)(q * MROWS + wi) * IJ + cl] = acc[tm][tn][r] / denom;
                }
            }
        }
    }
}

extern "C" void kernel_launch(void* const* d_in, const int* in_sizes, int n_in,
                              void* d_out, int out_size, void* d_ws, size_t ws_size,
                              hipStream_t stream) {
    const float* proto = (const float*)d_in[0];
    const float* query = (const float*)d_in[1];
    float* out = (float*)d_out;
    dim3 grid((MROWS + BM - 1) / BM, QN);   // 16 x 300
    sim_kernel<<<grid, THREADS, 0, stream>>>(proto, query, out);
}

// Round 2
// 469.630 us; speedup vs baseline: 1.3151x; 1.3151x over previous
//
#include <hip/hip_runtime.h>
#include <stdint.h>

#define QN    300
#define WN    10
#define CD    640
#define IJ    196
#define MROWS 1960              // WN*IJ
#define NTOT  58800             // QN*IJ
#define OUTQ  384160            // MROWS*IJ
#define EPSV  1e-8f

typedef __attribute__((ext_vector_type(8))) short bf16x8;
typedef __attribute__((ext_vector_type(4))) float f32x4;

__device__ __forceinline__ unsigned short f2bf(float f) {
    uint32_t u = __float_as_uint(f);
    u += 0x7FFFu + ((u >> 16) & 1u);   // RNE
    return (unsigned short)(u >> 16);
}

__device__ __forceinline__ void gload16(const void* g, void* l) {
    __builtin_amdgcn_global_load_lds(
        (const __attribute__((address_space(1))) void*)g,
        (__attribute__((address_space(3))) void*)l,
        16, 0, 0);
}

// ---------------------------------------------------------------------------
// Pre-pass: X[B][640][196] fp32 -> XT[B*196][640] bf16 (k contiguous, with the
// st_16x32 swizzle baked per 16B unit: unit ^= ((row>>2)&1)<<1), plus fp32
// norms nrm[B*196] = sqrt(sum_c x^2).
// ---------------------------------------------------------------------------
__global__ __launch_bounds__(256)
void prep_kernel(const float* __restrict__ X, uint4* __restrict__ XT,
                 float* __restrict__ nrm)
{
    __shared__ float T[128][21];
    __shared__ float ssL[16][17];

    const int b  = blockIdx.y;
    const int i0 = blockIdx.x * 16;
    const int t  = threadIdx.x;
    const float* Xb = X + (size_t)b * (CD * IJ);

    // phase-1 identity: thread reads float4 along i for one c-row
    const int cA  = t >> 2;              // 0..63 (c within pass)
    const int i4  = (t & 3) * 4;         // 0,4,8,12
    const int iv  = i0 + i4;
    const bool liv = (iv <= IJ - 4);     // full float4 in range (iv <= 192)

    // phase-2 identity: thread owns (i_local, 8-c unit)
    const int il = t >> 4;               // 0..15
    const int u  = t & 15;               // 0..15
    float ss = 0.f;

    const int ig   = i0 + il;
    const bool wok = (ig < IJ);
    const int rowg = b * IJ + (wok ? ig : IJ - 1);
    const int uxor = ((rowg >> 2) & 1) << 1;

    for (int cc = 0; cc < CD / 128; ++cc) {
        #pragma unroll
        for (int pass = 0; pass < 2; ++pass) {
            int cl = pass * 64 + cA;
            int c  = cc * 128 + cl;
            float4 v = make_float4(0.f, 0.f, 0.f, 0.f);
            if (liv) v = *(const float4*)&Xb[(size_t)c * IJ + iv];
            T[cl][i4 + 0] = v.x; T[cl][i4 + 1] = v.y;
            T[cl][i4 + 2] = v.z; T[cl][i4 + 3] = v.w;
        }
        __syncthreads();
        float v[8];
        #pragma unroll
        for (int r = 0; r < 8; ++r) { v[r] = T[u * 8 + r][il]; ss += v[r] * v[r]; }
        if (wok) {
            union { unsigned short s[8]; uint4 q; } pk;
            #pragma unroll
            for (int r = 0; r < 8; ++r) pk.s[r] = f2bf(v[r]);
            XT[(size_t)rowg * (CD / 8) + cc * 16 + (u ^ uxor)] = pk.q;
        }
        __syncthreads();
    }

    ssL[il][u] = ss;
    __syncthreads();
    if (t < 16) {
        int igw = i0 + t;
        if (igw < IJ) {
            float s = 0.f;
            #pragma unroll
            for (int k = 0; k < 16; ++k) s += ssL[t][k];
            nrm[b * IJ + igw] = sqrtf(s);
        }
    }
}

// ---------------------------------------------------------------------------
// GEMM: C[m][n] = sum_c AT[m][c]*BT[n][c], m<1960 (pad 2048), n<58800
// (pad 58880), K=640. 128x128 tile, BK=64, 4 waves, 4x4 acc of 16x16x32.
// Staging via global_load_lds dwordx4 from pre-swizzled bf16 arrays.
// ---------------------------------------------------------------------------
__global__ __launch_bounds__(256)
void gemm_kernel(const uint4* __restrict__ AT, const uint4* __restrict__ BT,
                 const float* __restrict__ pn, const float* __restrict__ qn,
                 float* __restrict__ out)
{
    __shared__ unsigned short As[128 * 64];
    __shared__ unsigned short Bs[128 * 64];

    const int t  = threadIdx.x;
    const int w  = t >> 6, l = t & 63;
    const int n0 = blockIdx.x * 128;
    const int m0 = blockIdx.y * 128;
    const int fr = l & 15, fq = l >> 4;
    const int wm0 = (w >> 1) * 64, wn0 = (w & 1) * 64;

    // staging: round r covers rows [r*32 + w*8, +8), lane: row += l>>3, unit l&7
    const int srow  = w * 8 + (l >> 3);
    const int sunit = l & 7;

    f32x4 acc[4][4];
    #pragma unroll
    for (int a = 0; a < 4; ++a)
        #pragma unroll
        for (int bb = 0; bb < 4; ++bb)
            acc[a][bb] = (f32x4){0.f, 0.f, 0.f, 0.f};

    for (int kk = 0; kk < CD / 64; ++kk) {
        #pragma unroll
        for (int r = 0; r < 4; ++r) {
            int ra = m0 + r * 32 + srow; if (ra > MROWS - 1) ra = MROWS - 1;
            gload16(AT + (size_t)ra * 80 + kk * 8 + sunit,
                    (char*)As + (r * 32 + w * 8) * 128);
            int rb = n0 + r * 32 + srow; if (rb > NTOT - 1) rb = NTOT - 1;
            gload16(BT + (size_t)rb * 80 + kk * 8 + sunit,
                    (char*)Bs + (r * 32 + w * 8) * 128);
        }
        __syncthreads();
        #pragma unroll
        for (int ks = 0; ks < 2; ++ks) {
            bf16x8 af[4], bfv[4];
            #pragma unroll
            for (int tm = 0; tm < 4; ++tm) {
                int row = wm0 + tm * 16 + fr;
                int idx = row * 64 + ((fq * 8 + ks * 32) ^ (((row >> 2) & 1) << 4));
                af[tm] = *(const bf16x8*)&As[idx];
            }
            #pragma unroll
            for (int tn = 0; tn < 4; ++tn) {
                int row = wn0 + tn * 16 + fr;
                int idx = row * 64 + ((fq * 8 + ks * 32) ^ (((row >> 2) & 1) << 4));
                bfv[tn] = *(const bf16x8*)&Bs[idx];
            }
            #pragma unroll
            for (int tm = 0; tm < 4; ++tm)
                #pragma unroll
                for (int tn = 0; tn < 4; ++tn)
                    acc[tm][tn] = __builtin_amdgcn_mfma_f32_16x16x32_bf16(
                        af[tm], bfv[tn], acc[tm][tn], 0, 0, 0);
        }
        __syncthreads();
    }

    // epilogue: out[q*OUTQ + m*196 + j] = acc / max(rp*rq, eps)
    float  rqv[4];
    int    nvalid[4];
    size_t obase[4];
    #pragma unroll
    for (int tn = 0; tn < 4; ++tn) {
        int n = n0 + wn0 + tn * 16 + fr;
        nvalid[tn] = (n < NTOT);
        int nc = nvalid[tn] ? n : NTOT - 1;
        int q  = nc / IJ;
        int j  = nc - q * IJ;
        rqv[tn]   = qn[nc];
        obase[tn] = (size_t)q * OUTQ + j;
    }
    #pragma unroll
    for (int tm = 0; tm < 4; ++tm) {
        #pragma unroll
        for (int rr = 0; rr < 4; ++rr) {
            int m = m0 + wm0 + tm * 16 + fq * 4 + rr;
            if (m < MROWS) {
                float rp = pn[m];
                #pragma unroll
                for (int tn = 0; tn < 4; ++tn) {
                    if (nvalid[tn]) {
                        float d = fmaxf(rp * rqv[tn], EPSV);
                        out[obase[tn] + (size_t)m * IJ] =
                            acc[tm][tn][rr] * __builtin_amdgcn_rcpf(d);
                    }
                }
            }
        }
    }
}

// ---------------------------------------------------------------------------
// Fallback (round-1 kernel, known-passing) if ws_size is insufficient.
// ---------------------------------------------------------------------------
#define BMF 128
#define BNF 224
#define LPAD 40
__global__ __launch_bounds__(512, 4)
void sim_fallback(const float* __restrict__ proto,
                  const float* __restrict__ query,
                  float* __restrict__ out)
{
    __shared__ unsigned short As[BMF][LPAD];
    __shared__ unsigned short Bs[BNF][LPAD];
    __shared__ float redA[4][BMF];
    __shared__ float redB[2][BNF];
    __shared__ float rpS[BMF];
    __shared__ float rqS[BNF];

    const int tid = threadIdx.x;
    const int m0  = blockIdx.x * BMF;
    const int q   = blockIdx.y;

    const int mA  = tid & (BMF - 1);
    const int krA = tid >> 7;
    const int wiA = m0 + mA;
    const bool va = (wiA < MROWS);
    const int wA  = va ? (wiA / IJ) : 0;
    const int iA  = va ? (wiA - wA * IJ) : 0;
    const float* pA = proto + wA * (CD * IJ) + iA;

    const bool tb  = (tid < 448);
    const int jB   = tb ? (tid % BNF) : 0;
    const int krB  = tb ? (tid / BNF) : 0;
    const bool vb  = tb && (jB < IJ);
    const float* qB = query + q * (CD * IJ) + jB;

    float ssA = 0.f, ssB = 0.f;

    const int wv   = tid >> 6;
    const int lane = tid & 63;
    const int wm0  = (wv >> 1) * 32;
    const int wn0  = (wv & 1) * 112;
    const int fr   = lane & 15;
    const int fq   = lane >> 4;

    f32x4 acc[2][7];
    #pragma unroll
    for (int a = 0; a < 2; a++)
        #pragma unroll
        for (int b = 0; b < 7; b++)
            acc[a][b] = (f32x4){0.f, 0.f, 0.f, 0.f};

    for (int it = 0; it < CD / 32; ++it) {
        const int c0 = it * 32;
        {
            float v[8];
            #pragma unroll
            for (int e = 0; e < 8; e++) {
                int c = c0 + krA * 8 + e;
                v[e] = va ? pA[c * IJ] : 0.f;
            }
            #pragma unroll
            for (int e = 0; e < 8; e++) ssA += v[e] * v[e];
            union { unsigned short s[8]; uint4 u; } pk;
            #pragma unroll
            for (int e = 0; e < 8; e++) pk.s[e] = f2bf(v[e]);
            *(uint4*)&As[mA][krA * 8] = pk.u;
        }
        if (tb) {
            #pragma unroll
            for (int h = 0; h < 2; ++h) {
                float v[8];
                #pragma unroll
                for (int e = 0; e < 8; e++) {
                    int c = c0 + krB * 16 + h * 8 + e;
                    v[e] = vb ? qB[c * IJ] : 0.f;
                }
                #pragma unroll
                for (int e = 0; e < 8; e++) ssB += v[e] * v[e];
                union { unsigned short s[8]; uint4 u; } pk;
                #pragma unroll
                for (int e = 0; e < 8; e++) pk.s[e] = f2bf(v[e]);
                *(uint4*)&Bs[jB][krB * 16 + h * 8] = pk.u;
            }
        }
        __syncthreads();
        bf16x8 af[2], bfv[7];
        #pragma unroll
        for (int tm = 0; tm < 2; tm++)
            af[tm] = *(const bf16x8*)&As[wm0 + tm * 16 + fr][fq * 8];
        #pragma unroll
        for (int tn = 0; tn < 7; tn++)
            bfv[tn] = *(const bf16x8*)&Bs[wn0 + tn * 16 + fr][fq * 8];
        #pragma unroll
        for (int tm = 0; tm < 2; tm++)
            #pragma unroll
            for (int tn = 0; tn < 7; tn++)
                acc[tm][tn] = __builtin_amdgcn_mfma_f32_16x16x32_bf16(
                    af[tm], bfv[tn], acc[tm][tn], 0, 0, 0);
        __syncthreads();
    }

    redA[krA][mA] = ssA;
    if (tb) redB[krB][jB] = ssB;
    __syncthreads();
    if (tid < BMF) {
        rpS[tid] = sqrtf(redA[0][tid] + redA[1][tid] + redA[2][tid] + redA[3][tid]);
    } else if (tid >= 256 && tid < 256 + BNF) {
        int j = tid - 256;
        rqS[j] = sqrtf(redB[0][j] + redB[1][j]);
    }
    __syncthreads();

    #pragma unroll
    for (int tm = 0; tm < 2; tm++) {
        #pragma unroll
        for (int tn = 0; tn < 7; tn++) {
            #pragma unroll
            for (int r = 0; r < 4; r++) {
                int rl = wm0 + tm * 16 + fq * 4 + r;
                int cl = wn0 + tn * 16 + fr;
                int wi = m0 + rl;
                if (wi < MROWS && cl < IJ) {
                    float denom = fmaxf(rpS[rl] * rqS[cl], 1e-8f);
                    out[(size_t)(q * MROWS + wi) * IJ + cl] = acc[tm][tn][r] / denom;
                }
            }
        }
    }
}

// ---------------------------------------------------------------------------
extern "C" void kernel_launch(void* const* d_in, const int* in_sizes, int n_in,
                              void* d_out, int out_size, void* d_ws, size_t ws_size,
                              hipStream_t stream) {
    const float* proto = (const float*)d_in[0];
    const float* query = (const float*)d_in[1];
    float* out = (float*)d_out;

    // workspace layout
    const size_t off_pT = 0;                       // 1960*640*2 = 2,508,800
    const size_t off_qT = 2508800;                 // 58800*640*2 = 75,264,000
    const size_t off_pn = 77772800;                // 1960*4
    const size_t off_qn = 77780736;                // 58800*4
    const size_t need   = 78015936;

    if (ws_size < need) {
        dim3 grid((MROWS + BMF - 1) / BMF, QN);
        sim_fallback<<<grid, 512, 0, stream>>>(proto, query, out);
        return;
    }

    char* ws = (char*)d_ws;
    uint4* pT = (uint4*)(ws + off_pT);
    uint4* qT = (uint4*)(ws + off_qT);
    float* pn = (float*)(ws + off_pn);
    float* qn = (float*)(ws + off_qn);

    prep_kernel<<<dim3(13, QN), 256, 0, stream>>>(query, qT, qn);
    prep_kernel<<<dim3(13, WN), 256, 0, stream>>>(proto, pT, pn);

    dim3 grid(460, 16);   // n-tiles x m-tiles
    gemm_kernel<<<grid, 256, 0, stream>>>(pT, qT, pn, qn, out);
}